// Round 6
// baseline (418.057 us; speedup 1.0000x reference)
//
#include <hip/hip_runtime.h>

typedef unsigned short us;
typedef __bf16 bf16x8 __attribute__((ext_vector_type(8)));
typedef float f32x4 __attribute__((ext_vector_type(4)));

#define MROWS 8192      // B*S
#define CDIM 1024
#define MC 8388608      // MROWS*CDIM
#define HEADSZ 131072   // S*D = 2048*64

__device__ __forceinline__ us f2bf(float f) {
    __bf16 h = (__bf16)f;
    return __builtin_bit_cast(us, h);
}

// async global->LDS, 16 B per lane, dst = wave-uniform base + lane*16
__device__ __forceinline__ void gl_lds16(const us* src, us* dst) {
    __builtin_amdgcn_global_load_lds(
        (const __attribute__((address_space(1))) void*)src,
        (__attribute__((address_space(3))) void*)dst, 16, 0, 0);
}

// ---------------- x fp32 -> bf16 ----------------
__global__ void cvt_x(const float* __restrict__ x, us* __restrict__ o, int n) {
    int i = (blockIdx.x * 256 + threadIdx.x) * 4;
    if (i >= n) return;
    float4 v = *(const float4*)(x + i);
    ushort4 r;
    r.x = f2bf(v.x); r.y = f2bf(v.y); r.z = f2bf(v.z); r.w = f2bf(v.w);
    *(ushort4*)(o + i) = r;
}

// ---------------- W (K x N) fp32 -> Wt (N x K) bf16 ----------------
__global__ void wtrans(const float* __restrict__ Wq, const float* __restrict__ Wk,
                       const float* __restrict__ Wv, const float* __restrict__ Wp,
                       us* __restrict__ dst) {
    __shared__ float tile[64][65];
    int z = blockIdx.z;
    const float* W = (z == 0) ? Wq : (z == 1) ? Wk : (z == 2) ? Wv : Wp;
    us* out = dst + (size_t)z * 1048576;
    int t = threadIdx.x;
    int k0 = blockIdx.x * 64, n0 = blockIdx.y * 64;
#pragma unroll
    for (int p = 0; p < 16; p++) {
        int idx = p * 256 + t, r = idx >> 6, c = idx & 63;
        tile[r][c] = W[(size_t)(k0 + r) * 1024 + n0 + c];
    }
    __syncthreads();
#pragma unroll
    for (int p = 0; p < 16; p++) {
        int idx = p * 256 + t, r = idx >> 6, c = idx & 63;  // r: n-offset, c: k-offset
        out[(size_t)(n0 + r) * 1024 + k0 + c] = f2bf(tile[c][r]);
    }
}

// ---------------- fused QKV GEMM: [8192x1024] x [3072x1024]^T ----------------
// m97-style staging. Grid (64 M-tiles, 24 N-tiles) M-major for A-tile L2
// reuse per XCD. All outputs written row-major into QKV[z]; z=0 (Q) scaled by
// 1/(8 ln2). (V^T handled by vtrans on contiguous head blocks — the faithful
// plain-view head split makes an in-epilogue transpose a scatter.)
__global__ __launch_bounds__(256) void gemmF(const us* __restrict__ A,
                                             const us* __restrict__ Wt,
                                             us* __restrict__ QKV) {
    __shared__ __align__(16) us As[128 * 32];
    __shared__ __align__(16) us Bs[128 * 32];
    const int K = 1024;
    int t = threadIdx.x;
    int w = t >> 6, l = t & 63;
    int wr = w >> 1, wc = w & 1;
    int lr = l & 15, lq = l >> 4;
    int m0 = blockIdx.x * 128, n0 = blockIdx.y * 128;

    int gg = (((l & 3) ^ ((l >> 3) & 3))) * 8;  // swizzled k-group
    int rr = 32 * w + (l >> 2);
    const us* srcA0 = A + (size_t)(m0 + rr) * K + gg;
    const us* srcA1 = srcA0 + (size_t)16 * K;
    const us* srcB0 = Wt + (size_t)(n0 + rr) * K + gg;
    const us* srcB1 = srcB0 + (size_t)16 * K;
    us* dA0 = As + w * 1024;
    us* dA1 = dA0 + 512;
    us* dB0 = Bs + w * 1024;
    us* dB1 = dB0 + 512;

    f32x4 zero4 = {0.f, 0.f, 0.f, 0.f};
    f32x4 acc[4][4];
#pragma unroll
    for (int i = 0; i < 4; i++)
#pragma unroll
        for (int j = 0; j < 4; j++) acc[i][j] = zero4;

    int sA = (lq ^ ((lr >> 1) & 3)) * 8;

    for (int k0 = 0; k0 < K; k0 += 32) {
        __syncthreads();
        gl_lds16(srcA0, dA0);
        gl_lds16(srcA1, dA1);
        gl_lds16(srcB0, dB0);
        gl_lds16(srcB1, dB1);
        srcA0 += 32; srcA1 += 32; srcB0 += 32; srcB1 += 32;
        __syncthreads();

        bf16x8 af[4], bf[4];
#pragma unroll
        for (int i = 0; i < 4; i++)
            af[i] = *reinterpret_cast<const bf16x8*>(&As[(wr * 64 + i * 16 + lr) * 32 + sA]);
#pragma unroll
        for (int i = 0; i < 4; i++)
            bf[i] = *reinterpret_cast<const bf16x8*>(&Bs[(wc * 64 + i * 16 + lr) * 32 + sA]);
#pragma unroll
        for (int mt = 0; mt < 4; mt++)
#pragma unroll
            for (int nt = 0; nt < 4; nt++)
                acc[mt][nt] = __builtin_amdgcn_mfma_f32_16x16x32_bf16(af[mt], bf[nt], acc[mt][nt], 0, 0, 0);
    }

    int z = n0 >> 10;
    float osc = (z == 0) ? 0.18033688011112042f : 1.0f;  // 1/(8*ln2) folded into Q
    us* C = QKV + (size_t)z * MC;
#pragma unroll
    for (int mt = 0; mt < 4; mt++)
#pragma unroll
        for (int nt = 0; nt < 4; nt++)
#pragma unroll
            for (int r = 0; r < 4; r++) {
                int row = m0 + wr * 64 + mt * 16 + lq * 4 + r;
                int col = (n0 & 1023) + wc * 64 + nt * 16 + lr;
                C[(size_t)row * 1024 + col] = f2bf(acc[mt][nt][r] * osc);
            }
}

// ---------------- proj GEMM: out[8192x1024] = ctx x Wp^T + bias (fp32) ------
__global__ __launch_bounds__(256) void gemmP(const us* __restrict__ A,
                                             const us* __restrict__ Bt,
                                             float* __restrict__ C,
                                             const float* __restrict__ bias) {
    __shared__ __align__(16) us As[128 * 32];
    __shared__ __align__(16) us Bs[128 * 32];
    const int K = 1024, N = 1024;
    int t = threadIdx.x;
    int w = t >> 6, l = t & 63;
    int wr = w >> 1, wc = w & 1;
    int lr = l & 15, lq = l >> 4;
    int m0 = blockIdx.x * 128, n0 = blockIdx.y * 128;

    int gg = (((l & 3) ^ ((l >> 3) & 3))) * 8;
    int rr = 32 * w + (l >> 2);
    const us* srcA0 = A + (size_t)(m0 + rr) * K + gg;
    const us* srcA1 = srcA0 + (size_t)16 * K;
    const us* srcB0 = Bt + (size_t)(n0 + rr) * K + gg;
    const us* srcB1 = srcB0 + (size_t)16 * K;
    us* dA0 = As + w * 1024;
    us* dA1 = dA0 + 512;
    us* dB0 = Bs + w * 1024;
    us* dB1 = dB0 + 512;

    f32x4 zero4 = {0.f, 0.f, 0.f, 0.f};
    f32x4 acc[4][4];
#pragma unroll
    for (int i = 0; i < 4; i++)
#pragma unroll
        for (int j = 0; j < 4; j++) acc[i][j] = zero4;

    int sA = (lq ^ ((lr >> 1) & 3)) * 8;

    for (int k0 = 0; k0 < K; k0 += 32) {
        __syncthreads();
        gl_lds16(srcA0, dA0);
        gl_lds16(srcA1, dA1);
        gl_lds16(srcB0, dB0);
        gl_lds16(srcB1, dB1);
        srcA0 += 32; srcA1 += 32; srcB0 += 32; srcB1 += 32;
        __syncthreads();

        bf16x8 af[4], bf[4];
#pragma unroll
        for (int i = 0; i < 4; i++)
            af[i] = *reinterpret_cast<const bf16x8*>(&As[(wr * 64 + i * 16 + lr) * 32 + sA]);
#pragma unroll
        for (int i = 0; i < 4; i++)
            bf[i] = *reinterpret_cast<const bf16x8*>(&Bs[(wc * 64 + i * 16 + lr) * 32 + sA]);
#pragma unroll
        for (int mt = 0; mt < 4; mt++)
#pragma unroll
            for (int nt = 0; nt < 4; nt++)
                acc[mt][nt] = __builtin_amdgcn_mfma_f32_16x16x32_bf16(af[mt], bf[nt], acc[mt][nt], 0, 0, 0);
    }

#pragma unroll
    for (int mt = 0; mt < 4; mt++)
#pragma unroll
        for (int nt = 0; nt < 4; nt++)
#pragma unroll
            for (int r = 0; r < 4; r++) {
                int row = m0 + wr * 64 + mt * 16 + lq * 4 + r;
                int col = n0 + wc * 64 + nt * 16 + lr;
                C[(size_t)row * N + col] = acc[mt][nt][r] + bias[col];
            }
}

// ---------------- V (per head-block 2048x64) -> Vt (64x2048) ----------------
// Pure contiguous-block transpose — correct under the faithful plain view.
__global__ void vtrans(const us* __restrict__ V, us* __restrict__ Vt) {
    __shared__ us tile[64][72];
    int t = threadIdx.x;
    const us* Vh = V + (size_t)blockIdx.y * HEADSZ;
    us* Vth = Vt + (size_t)blockIdx.y * HEADSZ;
    int kk0 = blockIdx.x * 64;
#pragma unroll
    for (int p = 0; p < 16; p++) {
        int idx = p * 256 + t, r = idx >> 6, c = idx & 63;
        tile[r][c] = Vh[(size_t)(kk0 + r) * 64 + c];
    }
    __syncthreads();
#pragma unroll
    for (int p = 0; p < 16; p++) {
        int idx = p * 256 + t, d = idx >> 6, c = idx & 63;
        Vth[(size_t)d * 2048 + kk0 + c] = tile[c][d];
    }
}

// ---------------- flash attention per (b,h), max-free, register-P ----------------
// grid: (16 q-tiles, 64 bh). 4 waves x 32 q-rows. K-tile 128.
// S^T = K.Q^T with K rows staged at permuted LDS rows rho(g) so packed-bf16
// score registers are verbatim the PV B-fragments (O^T = V^T . P^T). No max,
// no P LDS, no cross-lane ops in the K-loop. launch_bounds(256,4) pins
// 4 waves/SIMD; staging maps are phase-bank-uniform.
__global__ __launch_bounds__(256, 4) void attn(const us* __restrict__ QKV,
                                               const us* __restrict__ Vt,
                                               us* __restrict__ ctx) {
    __shared__ __align__(16) us Ks[128][72];    // 18432 B
    __shared__ __align__(16) us Vts[64][136];   // 17408 B

    int t = threadIdx.x, w = t >> 6, l = t & 63, lr = l & 15, lq = l >> 4;
    size_t hoff = (size_t)blockIdx.y * HEADSZ;
    const us* Qh = QKV + hoff;
    const us* Kh = QKV + MC + hoff;
    const us* Vth = Vt + hoff;
    int q0 = blockIdx.x * 128 + w * 32;

    // Q fragments (B operand of S^T MFMA); Q pre-scaled by 1/(8 ln2)
    bf16x8 bq[2][2];
#pragma unroll
    for (int mt = 0; mt < 2; mt++)
#pragma unroll
        for (int ks = 0; ks < 2; ks++)
            bq[mt][ks] = *reinterpret_cast<const bf16x8*>(Qh + (size_t)(q0 + mt * 16 + lr) * 64 + ks * 32 + lq * 8);

    f32x4 zero4 = {0.f, 0.f, 0.f, 0.f};
    f32x4 o[2][4];
    f32x4 rsv[2] = {zero4, zero4};
#pragma unroll
    for (int mt = 0; mt < 2; mt++)
#pragma unroll
        for (int nt = 0; nt < 4; nt++) o[mt][nt] = zero4;

    int vd = t & 63;          // V staging: phase-uniform banks
    int vc0 = (t >> 6) * 4;

    for (int kt = 0; kt < 16; kt++) {
        __syncthreads();
        {
            const us* src = Kh + (size_t)kt * 128 * 64;
#pragma unroll
            for (int p = 0; p < 4; p++) {
                int g = p * 32 + (t >> 3), ch = (t & 7) * 8;
                int srow = (g & ~0x1C) | ((g >> 1) & 0x0C) | ((g & 4) << 2);  // rho(g)
                *(uint4*)&Ks[srow][ch] = *(const uint4*)(src + (size_t)g * 64 + ch);
            }
            const us* vsrc = Vth + kt * 128;
#pragma unroll
            for (int p = 0; p < 4; p++) {
                int c = vc0 + p;
                *(uint4*)&Vts[vd][c * 8] = *(const uint4*)(vsrc + (size_t)vd * 2048 + c * 8);
            }
        }
        __syncthreads();

        // S^T tile: s[mt][nt][r] = score(qrow=q0+mt*16+lr, permuted-key nt*16+lq*4+r)
        f32x4 s[2][8];
#pragma unroll
        for (int mt = 0; mt < 2; mt++)
#pragma unroll
            for (int nt = 0; nt < 8; nt++) s[mt][nt] = zero4;
#pragma unroll
        for (int ks = 0; ks < 2; ks++)
#pragma unroll
            for (int nt = 0; nt < 8; nt++) {
                bf16x8 ak = *reinterpret_cast<const bf16x8*>(&Ks[nt * 16 + lr][ks * 32 + lq * 8]);
                s[0][nt] = __builtin_amdgcn_mfma_f32_16x16x32_bf16(ak, bq[0][ks], s[0][nt], 0, 0, 0);
                s[1][nt] = __builtin_amdgcn_mfma_f32_16x16x32_bf16(ak, bq[1][ks], s[1][nt], 0, 0, 0);
            }

        // p = exp2(s); per-lane row-sum; pack bf16 pairs -> PV B-fragments
        uint2 pp[2][8];
#pragma unroll
        for (int mt = 0; mt < 2; mt++)
#pragma unroll
            for (int nt = 0; nt < 8; nt++) {
                f32x4 sv = s[mt][nt];
                f32x4 p;
                p[0] = exp2f(sv[0]); p[1] = exp2f(sv[1]);
                p[2] = exp2f(sv[2]); p[3] = exp2f(sv[3]);
                rsv[mt][0] += p[0]; rsv[mt][1] += p[1];
                rsv[mt][2] += p[2]; rsv[mt][3] += p[3];
                pp[mt][nt].x = (uint)f2bf(p[0]) | ((uint)f2bf(p[1]) << 16);
                pp[mt][nt].y = (uint)f2bf(p[2]) | ((uint)f2bf(p[3]) << 16);
            }

        // O^T += V^T . P^T
#pragma unroll
        for (int kc = 0; kc < 4; kc++) {
            bf16x8 av[4];
#pragma unroll
            for (int dt = 0; dt < 4; dt++)
                av[dt] = *reinterpret_cast<const bf16x8*>(&Vts[dt * 16 + lr][kc * 32 + lq * 8]);
#pragma unroll
            for (int mt = 0; mt < 2; mt++) {
                bf16x8 bp = *reinterpret_cast<const bf16x8*>(&pp[mt][kc * 2]);
#pragma unroll
                for (int dt = 0; dt < 4; dt++)
                    o[mt][dt] = __builtin_amdgcn_mfma_f32_16x16x32_bf16(av[dt], bp, o[mt][dt], 0, 0, 0);
            }
        }
    }

    // finalize: lane owns q-col lr in O^T layout
    us* ch = ctx + hoff;
#pragma unroll
    for (int mt = 0; mt < 2; mt++) {
        float ls = (rsv[mt][0] + rsv[mt][1]) + (rsv[mt][2] + rsv[mt][3]);
        ls += __shfl_xor(ls, 16);
        ls += __shfl_xor(ls, 32);
        float linv = 1.0f / ls;
        int row = q0 + mt * 16 + lr;
#pragma unroll
        for (int dt = 0; dt < 4; dt++) {
            ushort4 pk;
            pk.x = f2bf(o[mt][dt][0] * linv);
            pk.y = f2bf(o[mt][dt][1] * linv);
            pk.z = f2bf(o[mt][dt][2] * linv);
            pk.w = f2bf(o[mt][dt][3] * linv);
            *(ushort4*)(ch + (size_t)row * 64 + dt * 16 + lq * 4) = pk;
        }
    }
}

extern "C" void kernel_launch(void* const* d_in, const int* in_sizes, int n_in,
                              void* d_out, int out_size, void* d_ws, size_t ws_size,
                              hipStream_t stream) {
    const float* x  = (const float*)d_in[0];
    const float* Wq = (const float*)d_in[1];
    const float* Wk = (const float*)d_in[2];
    const float* Wv = (const float*)d_in[3];
    const float* Wp = (const float*)d_in[4];
    const float* bp = (const float*)d_in[5];
    float* out = (float*)d_out;

    us* ws = (us*)d_ws;
    us* xb    = ws;                       // MC
    us* WtAll = xb + MC;                  // 4*1048576 (Wq,Wk,Wv,Wp transposed, stacked)
    us* QKV   = WtAll + 4 * 1048576;      // 3*MC (Q, K, V)
    us* VtB   = QKV + 3 * (size_t)MC;     // MC  (V^T per head-block)
    us* ctx   = VtB + MC;                 // MC

    cvt_x<<<MC / 1024, 256, 0, stream>>>(x, xb, MC);
    wtrans<<<dim3(16, 16, 4), 256, 0, stream>>>(Wq, Wk, Wv, Wp, WtAll);
    gemmF<<<dim3(64, 24), 256, 0, stream>>>(xb, WtAll, QKV);
    vtrans<<<dim3(32, 64), 256, 0, stream>>>(QKV + 2 * (size_t)MC, VtB);
    attn<<<dim3(16, 64), 256, 0, stream>>>(QKV, VtB, ctx);
    gemmP<<<dim3(64, 8), 256, 0, stream>>>(ctx, WtAll + 3 * 1048576, out, bp);
}

// Round 7
// 302.407 us; speedup vs baseline: 1.3824x; 1.3824x over previous
//
#include <hip/hip_runtime.h>

typedef unsigned short us;
typedef __bf16 bf16x8 __attribute__((ext_vector_type(8)));
typedef float f32x4 __attribute__((ext_vector_type(4)));

#define MROWS 8192      // B*S
#define CDIM 1024
#define MC 8388608      // MROWS*CDIM
#define HEADSZ 131072   // S*D = 2048*64

__device__ __forceinline__ us f2bf(float f) {
    __bf16 h = (__bf16)f;
    return __builtin_bit_cast(us, h);
}

// async global->LDS, 16 B per lane, dst = wave-uniform base + lane*16
__device__ __forceinline__ void gl_lds16(const us* src, us* dst) {
    __builtin_amdgcn_global_load_lds(
        (const __attribute__((address_space(1))) void*)src,
        (__attribute__((address_space(3))) void*)dst, 16, 0, 0);
}

// ---------------- x fp32 -> bf16 ----------------
__global__ void cvt_x(const float* __restrict__ x, us* __restrict__ o, int n) {
    int i = (blockIdx.x * 256 + threadIdx.x) * 4;
    if (i >= n) return;
    float4 v = *(const float4*)(x + i);
    ushort4 r;
    r.x = f2bf(v.x); r.y = f2bf(v.y); r.z = f2bf(v.z); r.w = f2bf(v.w);
    *(ushort4*)(o + i) = r;
}

// ---------------- W (K x N) fp32 -> Wt (N x K) bf16 ----------------
__global__ void wtrans(const float* __restrict__ Wq, const float* __restrict__ Wk,
                       const float* __restrict__ Wv, const float* __restrict__ Wp,
                       us* __restrict__ dst) {
    __shared__ float tile[64][65];
    int z = blockIdx.z;
    const float* W = (z == 0) ? Wq : (z == 1) ? Wk : (z == 2) ? Wv : Wp;
    us* out = dst + (size_t)z * 1048576;
    int t = threadIdx.x;
    int k0 = blockIdx.x * 64, n0 = blockIdx.y * 64;
#pragma unroll
    for (int p = 0; p < 16; p++) {
        int idx = p * 256 + t, r = idx >> 6, c = idx & 63;
        tile[r][c] = W[(size_t)(k0 + r) * 1024 + n0 + c];
    }
    __syncthreads();
#pragma unroll
    for (int p = 0; p < 16; p++) {
        int idx = p * 256 + t, r = idx >> 6, c = idx & 63;  // r: n-offset, c: k-offset
        out[(size_t)(n0 + r) * 1024 + k0 + c] = f2bf(tile[c][r]);
    }
}

// ---------------- fused QKV GEMM (async double-buffered) ----------------
// [8192x1024] x [3072x1024]^T. Prefetch tile k+1 after the barrier, compute
// tile k while the DMA flies. z=0 (Q) scaled by 1/(8 ln2).
__global__ __launch_bounds__(256) void gemmF(const us* __restrict__ A,
                                             const us* __restrict__ Wt,
                                             us* __restrict__ QKV) {
    __shared__ __align__(16) us As[2][128 * 32];
    __shared__ __align__(16) us Bs[2][128 * 32];
    const int K = 1024;
    int t = threadIdx.x;
    int w = t >> 6, l = t & 63;
    int wr = w >> 1, wc = w & 1;
    int lr = l & 15, lq = l >> 4;
    int m0 = blockIdx.x * 128, n0 = blockIdx.y * 128;

    int gg = (((l & 3) ^ ((l >> 3) & 3))) * 8;  // swizzled k-group
    int rr = 32 * w + (l >> 2);
    const us* srcA0 = A + (size_t)(m0 + rr) * K + gg;
    const us* srcA1 = srcA0 + (size_t)16 * K;
    const us* srcB0 = Wt + (size_t)(n0 + rr) * K + gg;
    const us* srcB1 = srcB0 + (size_t)16 * K;

    f32x4 zero4 = {0.f, 0.f, 0.f, 0.f};
    f32x4 acc[4][4];
#pragma unroll
    for (int i = 0; i < 4; i++)
#pragma unroll
        for (int j = 0; j < 4; j++) acc[i][j] = zero4;

    int sA = (lq ^ ((lr >> 1) & 3)) * 8;

    // prologue: prefetch tile 0 into buf 0
    gl_lds16(srcA0, As[0] + w * 1024);
    gl_lds16(srcA1, As[0] + w * 1024 + 512);
    gl_lds16(srcB0, Bs[0] + w * 1024);
    gl_lds16(srcB1, Bs[0] + w * 1024 + 512);

    for (int k0 = 0; k0 < K; k0 += 32) {
        int b = (k0 >> 5) & 1;
        __syncthreads();   // vmcnt(0) drain: tile k0 (prefetched last iter) now in LDS
        if (k0 + 32 < K) {
            int off = k0 + 32;
            int nb = b ^ 1;
            gl_lds16(srcA0 + off, As[nb] + w * 1024);
            gl_lds16(srcA1 + off, As[nb] + w * 1024 + 512);
            gl_lds16(srcB0 + off, Bs[nb] + w * 1024);
            gl_lds16(srcB1 + off, Bs[nb] + w * 1024 + 512);
        }
        const us* as = As[b];
        const us* bs = Bs[b];
        bf16x8 af[4], bf[4];
#pragma unroll
        for (int i = 0; i < 4; i++)
            af[i] = *reinterpret_cast<const bf16x8*>(&as[(wr * 64 + i * 16 + lr) * 32 + sA]);
#pragma unroll
        for (int i = 0; i < 4; i++)
            bf[i] = *reinterpret_cast<const bf16x8*>(&bs[(wc * 64 + i * 16 + lr) * 32 + sA]);
#pragma unroll
        for (int mt = 0; mt < 4; mt++)
#pragma unroll
            for (int nt = 0; nt < 4; nt++)
                acc[mt][nt] = __builtin_amdgcn_mfma_f32_16x16x32_bf16(af[mt], bf[nt], acc[mt][nt], 0, 0, 0);
    }

    int z = n0 >> 10;
    float osc = (z == 0) ? 0.18033688011112042f : 1.0f;  // 1/(8*ln2) folded into Q
    us* C = QKV + (size_t)z * MC;
#pragma unroll
    for (int mt = 0; mt < 4; mt++)
#pragma unroll
        for (int nt = 0; nt < 4; nt++)
#pragma unroll
            for (int r = 0; r < 4; r++) {
                int row = m0 + wr * 64 + mt * 16 + lq * 4 + r;
                int col = (n0 & 1023) + wc * 64 + nt * 16 + lr;
                C[(size_t)row * 1024 + col] = f2bf(acc[mt][nt][r] * osc);
            }
}

// ---------------- proj GEMM (async double-buffered, fp32 out + bias) --------
__global__ __launch_bounds__(256) void gemmP(const us* __restrict__ A,
                                             const us* __restrict__ Bt,
                                             float* __restrict__ C,
                                             const float* __restrict__ bias) {
    __shared__ __align__(16) us As[2][128 * 32];
    __shared__ __align__(16) us Bs[2][128 * 32];
    const int K = 1024, N = 1024;
    int t = threadIdx.x;
    int w = t >> 6, l = t & 63;
    int wr = w >> 1, wc = w & 1;
    int lr = l & 15, lq = l >> 4;
    int m0 = blockIdx.x * 128, n0 = blockIdx.y * 128;

    int gg = (((l & 3) ^ ((l >> 3) & 3))) * 8;
    int rr = 32 * w + (l >> 2);
    const us* srcA0 = A + (size_t)(m0 + rr) * K + gg;
    const us* srcA1 = srcA0 + (size_t)16 * K;
    const us* srcB0 = Bt + (size_t)(n0 + rr) * K + gg;
    const us* srcB1 = srcB0 + (size_t)16 * K;

    f32x4 zero4 = {0.f, 0.f, 0.f, 0.f};
    f32x4 acc[4][4];
#pragma unroll
    for (int i = 0; i < 4; i++)
#pragma unroll
        for (int j = 0; j < 4; j++) acc[i][j] = zero4;

    int sA = (lq ^ ((lr >> 1) & 3)) * 8;

    gl_lds16(srcA0, As[0] + w * 1024);
    gl_lds16(srcA1, As[0] + w * 1024 + 512);
    gl_lds16(srcB0, Bs[0] + w * 1024);
    gl_lds16(srcB1, Bs[0] + w * 1024 + 512);

    for (int k0 = 0; k0 < K; k0 += 32) {
        int b = (k0 >> 5) & 1;
        __syncthreads();
        if (k0 + 32 < K) {
            int off = k0 + 32;
            int nb = b ^ 1;
            gl_lds16(srcA0 + off, As[nb] + w * 1024);
            gl_lds16(srcA1 + off, As[nb] + w * 1024 + 512);
            gl_lds16(srcB0 + off, Bs[nb] + w * 1024);
            gl_lds16(srcB1 + off, Bs[nb] + w * 1024 + 512);
        }
        const us* as = As[b];
        const us* bs = Bs[b];
        bf16x8 af[4], bf[4];
#pragma unroll
        for (int i = 0; i < 4; i++)
            af[i] = *reinterpret_cast<const bf16x8*>(&as[(wr * 64 + i * 16 + lr) * 32 + sA]);
#pragma unroll
        for (int i = 0; i < 4; i++)
            bf[i] = *reinterpret_cast<const bf16x8*>(&bs[(wc * 64 + i * 16 + lr) * 32 + sA]);
#pragma unroll
        for (int mt = 0; mt < 4; mt++)
#pragma unroll
            for (int nt = 0; nt < 4; nt++)
                acc[mt][nt] = __builtin_amdgcn_mfma_f32_16x16x32_bf16(af[mt], bf[nt], acc[mt][nt], 0, 0, 0);
    }

#pragma unroll
    for (int mt = 0; mt < 4; mt++)
#pragma unroll
        for (int nt = 0; nt < 4; nt++)
#pragma unroll
            for (int r = 0; r < 4; r++) {
                int row = m0 + wr * 64 + mt * 16 + lq * 4 + r;
                int col = n0 + wc * 64 + nt * 16 + lr;
                C[(size_t)row * N + col] = acc[mt][nt][r] + bias[col];
            }
}

// ---------------- V (per head-block 2048x64) -> Vt (64x2048) ----------------
__global__ void vtrans(const us* __restrict__ V, us* __restrict__ Vt) {
    __shared__ us tile[64][72];
    int t = threadIdx.x;
    const us* Vh = V + (size_t)blockIdx.y * HEADSZ;
    us* Vth = Vt + (size_t)blockIdx.y * HEADSZ;
    int kk0 = blockIdx.x * 64;
#pragma unroll
    for (int p = 0; p < 16; p++) {
        int idx = p * 256 + t, r = idx >> 6, c = idx & 63;
        tile[r][c] = Vh[(size_t)(kk0 + r) * 64 + c];
    }
    __syncthreads();
#pragma unroll
    for (int p = 0; p < 16; p++) {
        int idx = p * 256 + t, d = idx >> 6, c = idx & 63;
        Vth[(size_t)d * 2048 + kk0 + c] = tile[c][d];
    }
}

// ---------------- flash attention, async double-buffered K-loop -------------
// grid: (16 q-tiles, 64 bh). 4 waves x 32 q-rows. K-tile 128.
// S^T = K.Q^T (K rows at permuted rows rho(g)); packed scores are verbatim
// the PV B-fragments (O^T = V^T.P^T). Max-free softmax. K/V staged by
// global_load_lds into contiguous XOR-swizzled tiles; tile t+1 prefetched
// after the barrier so its DMA latency overlaps compute of tile t.
__global__ __launch_bounds__(256, 2) void attn(const us* __restrict__ QKV,
                                               const us* __restrict__ Vt,
                                               us* __restrict__ ctx) {
    __shared__ __align__(16) us Ks[2][128 * 64];   // 2 x 16 KB
    __shared__ __align__(16) us Vts[2][64 * 128];  // 2 x 16 KB

    int t = threadIdx.x, w = t >> 6, l = t & 63, lr = l & 15, lq = l >> 4;
    size_t hoff = (size_t)blockIdx.y * HEADSZ;
    const us* Qh = QKV + hoff;
    const us* Kh = QKV + MC + hoff;
    const us* Vth = Vt + hoff;
    int q0 = blockIdx.x * 128 + w * 32;

    // ---- staging maps (per wave, 4 calls each for K and V) ----
    // K: LDS rows R = 32w+8c+(l>>3); slot l&7 holds d-group (l&7)^(l>>3);
    //    global key g = rhoinv(R).
    int kRb = 32 * w;                       // + 8c
    int kRl = l >> 3;                       // lane row within call
    int kGrp = ((l & 7) ^ kRl) * 8;         // global d offset (elements)
    // V: LDS rows d = 16w+4c+(l>>4); slot l&15 holds col-group (l&15)^(d&7).
    int vDb = 16 * w;

    // Q fragments (B operand of S^T MFMA); Q pre-scaled by 1/(8 ln2)
    bf16x8 bq[2][2];
#pragma unroll
    for (int mt = 0; mt < 2; mt++)
#pragma unroll
        for (int ks = 0; ks < 2; ks++)
            bq[mt][ks] = *reinterpret_cast<const bf16x8*>(Qh + (size_t)(q0 + mt * 16 + lr) * 64 + ks * 32 + lq * 8);

    f32x4 zero4 = {0.f, 0.f, 0.f, 0.f};
    f32x4 o[2][4];
    f32x4 rsv[2] = {zero4, zero4};
#pragma unroll
    for (int mt = 0; mt < 2; mt++)
#pragma unroll
        for (int nt = 0; nt < 4; nt++) o[mt][nt] = zero4;

    // prefetch helper (macro-ish lambda): stage tile kt into buffer bb
    auto stage = [&](int kt, int bb) {
        const us* ksrc = Kh + (size_t)kt * 8192;
        const us* vsrc = Vth + kt * 128;
#pragma unroll
        for (int c = 0; c < 4; c++) {
            int R = kRb + 8 * c + kRl;
            int g = (R & ~0x1C) | ((R & 0x0C) << 1) | ((R >> 2) & 4);  // rho^{-1}
            gl_lds16(ksrc + (size_t)g * 64 + kGrp, Ks[bb] + (kRb + 8 * c) * 64);
        }
#pragma unroll
        for (int c = 0; c < 4; c++) {
            int d = vDb + 4 * c + (l >> 4);
            int gc = ((l & 15) ^ (d & 7)) * 8;
            gl_lds16(vsrc + (size_t)d * 2048 + gc, Vts[bb] + (vDb + 4 * c) * 128);
        }
    };

    stage(0, 0);

    for (int kt = 0; kt < 16; kt++) {
        int b = kt & 1;
        __syncthreads();            // drains vmcnt -> tile kt resident in buf b
        if (kt < 15) stage(kt + 1, b ^ 1);
        const us* ksb = Ks[b];
        const us* vtb = Vts[b];

        // S^T tile: s[mt][nt][r] = score(qrow=q0+mt*16+lr, permuted-key nt*16+lq*4+r)
        f32x4 s[2][8];
#pragma unroll
        for (int mt = 0; mt < 2; mt++)
#pragma unroll
            for (int nt = 0; nt < 8; nt++) s[mt][nt] = zero4;
#pragma unroll
        for (int ks = 0; ks < 2; ks++) {
            int swz = ((ks * 4 + lq) ^ (lr & 7)) * 8;
#pragma unroll
            for (int nt = 0; nt < 8; nt++) {
                bf16x8 ak = *reinterpret_cast<const bf16x8*>(&ksb[(nt * 16 + lr) * 64 + swz]);
                s[0][nt] = __builtin_amdgcn_mfma_f32_16x16x32_bf16(ak, bq[0][ks], s[0][nt], 0, 0, 0);
                s[1][nt] = __builtin_amdgcn_mfma_f32_16x16x32_bf16(ak, bq[1][ks], s[1][nt], 0, 0, 0);
            }
        }

        // p = exp2(s); per-lane row-sum; pack bf16 pairs -> PV B-fragments
        uint2 pp[2][8];
#pragma unroll
        for (int mt = 0; mt < 2; mt++)
#pragma unroll
            for (int nt = 0; nt < 8; nt++) {
                f32x4 sv = s[mt][nt];
                f32x4 p;
                p[0] = exp2f(sv[0]); p[1] = exp2f(sv[1]);
                p[2] = exp2f(sv[2]); p[3] = exp2f(sv[3]);
                rsv[mt][0] += p[0]; rsv[mt][1] += p[1];
                rsv[mt][2] += p[2]; rsv[mt][3] += p[3];
                pp[mt][nt].x = (uint)f2bf(p[0]) | ((uint)f2bf(p[1]) << 16);
                pp[mt][nt].y = (uint)f2bf(p[2]) | ((uint)f2bf(p[3]) << 16);
            }

        // O^T += V^T . P^T
#pragma unroll
        for (int kc = 0; kc < 4; kc++) {
            int swv = ((kc * 4 + lq) ^ (lr & 7)) * 8;
            bf16x8 av[4];
#pragma unroll
            for (int dt = 0; dt < 4; dt++)
                av[dt] = *reinterpret_cast<const bf16x8*>(&vtb[(dt * 16 + lr) * 128 + swv]);
#pragma unroll
            for (int mt = 0; mt < 2; mt++) {
                bf16x8 bp = *reinterpret_cast<const bf16x8*>(&pp[mt][kc * 2]);
#pragma unroll
                for (int dt = 0; dt < 4; dt++)
                    o[mt][dt] = __builtin_amdgcn_mfma_f32_16x16x32_bf16(av[dt], bp, o[mt][dt], 0, 0, 0);
            }
        }
    }

    // finalize: lane owns q-col lr in O^T layout
    us* ch = ctx + hoff;
#pragma unroll
    for (int mt = 0; mt < 2; mt++) {
        float ls = (rsv[mt][0] + rsv[mt][1]) + (rsv[mt][2] + rsv[mt][3]);
        ls += __shfl_xor(ls, 16);
        ls += __shfl_xor(ls, 32);
        float linv = 1.0f / ls;
        int row = q0 + mt * 16 + lr;
#pragma unroll
        for (int dt = 0; dt < 4; dt++) {
            ushort4 pk;
            pk.x = f2bf(o[mt][dt][0] * linv);
            pk.y = f2bf(o[mt][dt][1] * linv);
            pk.z = f2bf(o[mt][dt][2] * linv);
            pk.w = f2bf(o[mt][dt][3] * linv);
            *(ushort4*)(ch + (size_t)row * 64 + dt * 16 + lq * 4) = pk;
        }
    }
}

extern "C" void kernel_launch(void* const* d_in, const int* in_sizes, int n_in,
                              void* d_out, int out_size, void* d_ws, size_t ws_size,
                              hipStream_t stream) {
    const float* x  = (const float*)d_in[0];
    const float* Wq = (const float*)d_in[1];
    const float* Wk = (const float*)d_in[2];
    const float* Wv = (const float*)d_in[3];
    const float* Wp = (const float*)d_in[4];
    const float* bp = (const float*)d_in[5];
    float* out = (float*)d_out;

    us* ws = (us*)d_ws;
    us* xb    = ws;                       // MC
    us* WtAll = xb + MC;                  // 4*1048576 (Wq,Wk,Wv,Wp transposed, stacked)
    us* QKV   = WtAll + 4 * 1048576;      // 3*MC (Q, K, V)
    us* VtB   = QKV + 3 * (size_t)MC;     // MC  (V^T per head-block)
    us* ctx   = VtB + MC;                 // MC

    cvt_x<<<MC / 1024, 256, 0, stream>>>(x, xb, MC);
    wtrans<<<dim3(16, 16, 4), 256, 0, stream>>>(Wq, Wk, Wv, Wp, WtAll);
    gemmF<<<dim3(64, 24), 256, 0, stream>>>(xb, WtAll, QKV);
    vtrans<<<dim3(32, 64), 256, 0, stream>>>(QKV + 2 * (size_t)MC, VtB);
    attn<<<dim3(16, 64), 256, 0, stream>>>(QKV, VtB, ctx);
    gemmP<<<dim3(64, 8), 256, 0, stream>>>(ctx, WtAll + 3 * 1048576, out, bp);
}

// Round 8
// 298.202 us; speedup vs baseline: 1.4019x; 1.0141x over previous
//
#include <hip/hip_runtime.h>

typedef unsigned short us;
typedef __bf16 bf16x8 __attribute__((ext_vector_type(8)));
typedef float f32x4 __attribute__((ext_vector_type(4)));

#define MROWS 8192      // B*S
#define CDIM 1024
#define MC 8388608      // MROWS*CDIM
#define HEADSZ 131072   // S*D = 2048*64

__device__ __forceinline__ us f2bf(float f) {
    __bf16 h = (__bf16)f;
    return __builtin_bit_cast(us, h);
}

// async global->LDS, 16 B per lane, dst = wave-uniform base + lane*16
__device__ __forceinline__ void gl_lds16(const us* src, us* dst) {
    __builtin_amdgcn_global_load_lds(
        (const __attribute__((address_space(1))) void*)src,
        (__attribute__((address_space(3))) void*)dst, 16, 0, 0);
}

// ---------------- x fp32 -> bf16 ----------------
__global__ void cvt_x(const float* __restrict__ x, us* __restrict__ o, int n) {
    int i = (blockIdx.x * 256 + threadIdx.x) * 4;
    if (i >= n) return;
    float4 v = *(const float4*)(x + i);
    ushort4 r;
    r.x = f2bf(v.x); r.y = f2bf(v.y); r.z = f2bf(v.z); r.w = f2bf(v.w);
    *(ushort4*)(o + i) = r;
}

// ---------------- W (K x N) fp32 -> Wt (N x K) bf16 ----------------
__global__ void wtrans(const float* __restrict__ Wq, const float* __restrict__ Wk,
                       const float* __restrict__ Wv, const float* __restrict__ Wp,
                       us* __restrict__ dst) {
    __shared__ float tile[64][65];
    int z = blockIdx.z;
    const float* W = (z == 0) ? Wq : (z == 1) ? Wk : (z == 2) ? Wv : Wp;
    us* out = dst + (size_t)z * 1048576;
    int t = threadIdx.x;
    int k0 = blockIdx.x * 64, n0 = blockIdx.y * 64;
#pragma unroll
    for (int p = 0; p < 16; p++) {
        int idx = p * 256 + t, r = idx >> 6, c = idx & 63;
        tile[r][c] = W[(size_t)(k0 + r) * 1024 + n0 + c];
    }
    __syncthreads();
#pragma unroll
    for (int p = 0; p < 16; p++) {
        int idx = p * 256 + t, r = idx >> 6, c = idx & 63;  // r: n-offset, c: k-offset
        out[(size_t)(n0 + r) * 1024 + k0 + c] = f2bf(tile[c][r]);
    }
}

// ---------------- fused QKV GEMM (async double-buffered) ----------------
// [8192x1024] x [3072x1024]^T. Prefetch tile k+1 after the barrier, compute
// tile k while the DMA flies. z=0 (Q) scaled by 1/(8 ln2).
__global__ __launch_bounds__(256) void gemmF(const us* __restrict__ A,
                                             const us* __restrict__ Wt,
                                             us* __restrict__ QKV) {
    __shared__ __align__(16) us As[2][128 * 32];
    __shared__ __align__(16) us Bs[2][128 * 32];
    const int K = 1024;
    int t = threadIdx.x;
    int w = t >> 6, l = t & 63;
    int wr = w >> 1, wc = w & 1;
    int lr = l & 15, lq = l >> 4;
    int m0 = blockIdx.x * 128, n0 = blockIdx.y * 128;

    int gg = (((l & 3) ^ ((l >> 3) & 3))) * 8;  // swizzled k-group
    int rr = 32 * w + (l >> 2);
    const us* srcA0 = A + (size_t)(m0 + rr) * K + gg;
    const us* srcA1 = srcA0 + (size_t)16 * K;
    const us* srcB0 = Wt + (size_t)(n0 + rr) * K + gg;
    const us* srcB1 = srcB0 + (size_t)16 * K;

    f32x4 zero4 = {0.f, 0.f, 0.f, 0.f};
    f32x4 acc[4][4];
#pragma unroll
    for (int i = 0; i < 4; i++)
#pragma unroll
        for (int j = 0; j < 4; j++) acc[i][j] = zero4;

    int sA = (lq ^ ((lr >> 1) & 3)) * 8;

    // prologue: prefetch tile 0 into buf 0
    gl_lds16(srcA0, As[0] + w * 1024);
    gl_lds16(srcA1, As[0] + w * 1024 + 512);
    gl_lds16(srcB0, Bs[0] + w * 1024);
    gl_lds16(srcB1, Bs[0] + w * 1024 + 512);

    for (int k0 = 0; k0 < K; k0 += 32) {
        int b = (k0 >> 5) & 1;
        __syncthreads();   // vmcnt(0) drain: tile k0 (prefetched last iter) now in LDS
        if (k0 + 32 < K) {
            int off = k0 + 32;
            int nb = b ^ 1;
            gl_lds16(srcA0 + off, As[nb] + w * 1024);
            gl_lds16(srcA1 + off, As[nb] + w * 1024 + 512);
            gl_lds16(srcB0 + off, Bs[nb] + w * 1024);
            gl_lds16(srcB1 + off, Bs[nb] + w * 1024 + 512);
        }
        const us* as = As[b];
        const us* bs = Bs[b];
        bf16x8 af[4], bf[4];
#pragma unroll
        for (int i = 0; i < 4; i++)
            af[i] = *reinterpret_cast<const bf16x8*>(&as[(wr * 64 + i * 16 + lr) * 32 + sA]);
#pragma unroll
        for (int i = 0; i < 4; i++)
            bf[i] = *reinterpret_cast<const bf16x8*>(&bs[(wc * 64 + i * 16 + lr) * 32 + sA]);
#pragma unroll
        for (int mt = 0; mt < 4; mt++)
#pragma unroll
            for (int nt = 0; nt < 4; nt++)
                acc[mt][nt] = __builtin_amdgcn_mfma_f32_16x16x32_bf16(af[mt], bf[nt], acc[mt][nt], 0, 0, 0);
    }

    int z = n0 >> 10;
    float osc = (z == 0) ? 0.18033688011112042f : 1.0f;  // 1/(8*ln2) folded into Q
    us* C = QKV + (size_t)z * MC;
#pragma unroll
    for (int mt = 0; mt < 4; mt++)
#pragma unroll
        for (int nt = 0; nt < 4; nt++)
#pragma unroll
            for (int r = 0; r < 4; r++) {
                int row = m0 + wr * 64 + mt * 16 + lq * 4 + r;
                int col = (n0 & 1023) + wc * 64 + nt * 16 + lr;
                C[(size_t)row * 1024 + col] = f2bf(acc[mt][nt][r] * osc);
            }
}

// ---------------- proj GEMM (async double-buffered, fp32 out + bias) --------
__global__ __launch_bounds__(256) void gemmP(const us* __restrict__ A,
                                             const us* __restrict__ Bt,
                                             float* __restrict__ C,
                                             const float* __restrict__ bias) {
    __shared__ __align__(16) us As[2][128 * 32];
    __shared__ __align__(16) us Bs[2][128 * 32];
    const int K = 1024, N = 1024;
    int t = threadIdx.x;
    int w = t >> 6, l = t & 63;
    int wr = w >> 1, wc = w & 1;
    int lr = l & 15, lq = l >> 4;
    int m0 = blockIdx.x * 128, n0 = blockIdx.y * 128;

    int gg = (((l & 3) ^ ((l >> 3) & 3))) * 8;
    int rr = 32 * w + (l >> 2);
    const us* srcA0 = A + (size_t)(m0 + rr) * K + gg;
    const us* srcA1 = srcA0 + (size_t)16 * K;
    const us* srcB0 = Bt + (size_t)(n0 + rr) * K + gg;
    const us* srcB1 = srcB0 + (size_t)16 * K;

    f32x4 zero4 = {0.f, 0.f, 0.f, 0.f};
    f32x4 acc[4][4];
#pragma unroll
    for (int i = 0; i < 4; i++)
#pragma unroll
        for (int j = 0; j < 4; j++) acc[i][j] = zero4;

    int sA = (lq ^ ((lr >> 1) & 3)) * 8;

    gl_lds16(srcA0, As[0] + w * 1024);
    gl_lds16(srcA1, As[0] + w * 1024 + 512);
    gl_lds16(srcB0, Bs[0] + w * 1024);
    gl_lds16(srcB1, Bs[0] + w * 1024 + 512);

    for (int k0 = 0; k0 < K; k0 += 32) {
        int b = (k0 >> 5) & 1;
        __syncthreads();
        if (k0 + 32 < K) {
            int off = k0 + 32;
            int nb = b ^ 1;
            gl_lds16(srcA0 + off, As[nb] + w * 1024);
            gl_lds16(srcA1 + off, As[nb] + w * 1024 + 512);
            gl_lds16(srcB0 + off, Bs[nb] + w * 1024);
            gl_lds16(srcB1 + off, Bs[nb] + w * 1024 + 512);
        }
        const us* as = As[b];
        const us* bs = Bs[b];
        bf16x8 af[4], bf[4];
#pragma unroll
        for (int i = 0; i < 4; i++)
            af[i] = *reinterpret_cast<const bf16x8*>(&as[(wr * 64 + i * 16 + lr) * 32 + sA]);
#pragma unroll
        for (int i = 0; i < 4; i++)
            bf[i] = *reinterpret_cast<const bf16x8*>(&bs[(wc * 64 + i * 16 + lr) * 32 + sA]);
#pragma unroll
        for (int mt = 0; mt < 4; mt++)
#pragma unroll
            for (int nt = 0; nt < 4; nt++)
                acc[mt][nt] = __builtin_amdgcn_mfma_f32_16x16x32_bf16(af[mt], bf[nt], acc[mt][nt], 0, 0, 0);
    }

#pragma unroll
    for (int mt = 0; mt < 4; mt++)
#pragma unroll
        for (int nt = 0; nt < 4; nt++)
#pragma unroll
            for (int r = 0; r < 4; r++) {
                int row = m0 + wr * 64 + mt * 16 + lq * 4 + r;
                int col = n0 + wc * 64 + nt * 16 + lr;
                C[(size_t)row * N + col] = acc[mt][nt][r] + bias[col];
            }
}

// ---------------- V (per head-block 2048x64) -> Vt (64x2048) ----------------
__global__ void vtrans(const us* __restrict__ V, us* __restrict__ Vt) {
    __shared__ us tile[64][72];
    int t = threadIdx.x;
    const us* Vh = V + (size_t)blockIdx.y * HEADSZ;
    us* Vth = Vt + (size_t)blockIdx.y * HEADSZ;
    int kk0 = blockIdx.x * 64;
#pragma unroll
    for (int p = 0; p < 16; p++) {
        int idx = p * 256 + t, r = idx >> 6, c = idx & 63;
        tile[r][c] = Vh[(size_t)(kk0 + r) * 64 + c];
    }
    __syncthreads();
#pragma unroll
    for (int p = 0; p < 16; p++) {
        int idx = p * 256 + t, d = idx >> 6, c = idx & 63;
        Vth[(size_t)d * 2048 + kk0 + c] = tile[c][d];
    }
}

// ---------------- flash attention, async double-buffered K-loop -------------
// grid: (64 bh, 16 q-tiles) — bh is blockIdx.x so XCD = bh%8: all 16 q-tile
// blocks of a head run on ONE XCD; per-XCD K/V working set = 8 heads x 512 KB
// = 4 MB = L2 size. K/V staging hits L2 instead of HBM.
// S^T = K.Q^T (K rows at permuted rows rho(g)); packed scores are verbatim
// the PV B-fragments (O^T = V^T.P^T). Max-free softmax.
__global__ __launch_bounds__(256, 2) void attn(const us* __restrict__ QKV,
                                               const us* __restrict__ Vt,
                                               us* __restrict__ ctx) {
    __shared__ __align__(16) us Ks[2][128 * 64];   // 2 x 16 KB
    __shared__ __align__(16) us Vts[2][64 * 128];  // 2 x 16 KB

    int t = threadIdx.x, w = t >> 6, l = t & 63, lr = l & 15, lq = l >> 4;
    size_t hoff = (size_t)blockIdx.x * HEADSZ;
    const us* Qh = QKV + hoff;
    const us* Kh = QKV + MC + hoff;
    const us* Vth = Vt + hoff;
    int q0 = blockIdx.y * 128 + w * 32;

    // ---- staging maps (per wave, 4 calls each for K and V) ----
    int kRb = 32 * w;                       // + 8c
    int kRl = l >> 3;                       // lane row within call
    int kGrp = ((l & 7) ^ kRl) * 8;         // global d offset (elements)
    int vDb = 16 * w;

    // Q fragments (B operand of S^T MFMA); Q pre-scaled by 1/(8 ln2)
    bf16x8 bq[2][2];
#pragma unroll
    for (int mt = 0; mt < 2; mt++)
#pragma unroll
        for (int ks = 0; ks < 2; ks++)
            bq[mt][ks] = *reinterpret_cast<const bf16x8*>(Qh + (size_t)(q0 + mt * 16 + lr) * 64 + ks * 32 + lq * 8);

    f32x4 zero4 = {0.f, 0.f, 0.f, 0.f};
    f32x4 o[2][4];
    f32x4 rsv[2] = {zero4, zero4};
#pragma unroll
    for (int mt = 0; mt < 2; mt++)
#pragma unroll
        for (int nt = 0; nt < 4; nt++) o[mt][nt] = zero4;

    auto stage = [&](int kt, int bb) {
        const us* ksrc = Kh + (size_t)kt * 8192;
        const us* vsrc = Vth + kt * 128;
#pragma unroll
        for (int c = 0; c < 4; c++) {
            int R = kRb + 8 * c + kRl;
            int g = (R & ~0x1C) | ((R & 0x0C) << 1) | ((R >> 2) & 4);  // rho^{-1}
            gl_lds16(ksrc + (size_t)g * 64 + kGrp, Ks[bb] + (kRb + 8 * c) * 64);
        }
#pragma unroll
        for (int c = 0; c < 4; c++) {
            int d = vDb + 4 * c + (l >> 4);
            int gc = ((l & 15) ^ (d & 7)) * 8;
            gl_lds16(vsrc + (size_t)d * 2048 + gc, Vts[bb] + (vDb + 4 * c) * 128);
        }
    };

    stage(0, 0);

    for (int kt = 0; kt < 16; kt++) {
        int b = kt & 1;
        __syncthreads();            // drains vmcnt -> tile kt resident in buf b
        if (kt < 15) stage(kt + 1, b ^ 1);
        const us* ksb = Ks[b];
        const us* vtb = Vts[b];

        // S^T tile: s[mt][nt][r] = score(qrow=q0+mt*16+lr, permuted-key nt*16+lq*4+r)
        f32x4 s[2][8];
#pragma unroll
        for (int mt = 0; mt < 2; mt++)
#pragma unroll
            for (int nt = 0; nt < 8; nt++) s[mt][nt] = zero4;
#pragma unroll
        for (int ks = 0; ks < 2; ks++) {
            int swz = ((ks * 4 + lq) ^ (lr & 7)) * 8;
#pragma unroll
            for (int nt = 0; nt < 8; nt++) {
                bf16x8 ak = *reinterpret_cast<const bf16x8*>(&ksb[(nt * 16 + lr) * 64 + swz]);
                s[0][nt] = __builtin_amdgcn_mfma_f32_16x16x32_bf16(ak, bq[0][ks], s[0][nt], 0, 0, 0);
                s[1][nt] = __builtin_amdgcn_mfma_f32_16x16x32_bf16(ak, bq[1][ks], s[1][nt], 0, 0, 0);
            }
        }

        // p = exp2(s); per-lane row-sum; pack bf16 pairs -> PV B-fragments
        uint2 pp[2][8];
#pragma unroll
        for (int mt = 0; mt < 2; mt++)
#pragma unroll
            for (int nt = 0; nt < 8; nt++) {
                f32x4 sv = s[mt][nt];
                f32x4 p;
                p[0] = exp2f(sv[0]); p[1] = exp2f(sv[1]);
                p[2] = exp2f(sv[2]); p[3] = exp2f(sv[3]);
                rsv[mt][0] += p[0]; rsv[mt][1] += p[1];
                rsv[mt][2] += p[2]; rsv[mt][3] += p[3];
                pp[mt][nt].x = (uint)f2bf(p[0]) | ((uint)f2bf(p[1]) << 16);
                pp[mt][nt].y = (uint)f2bf(p[2]) | ((uint)f2bf(p[3]) << 16);
            }

        // O^T += V^T . P^T
#pragma unroll
        for (int kc = 0; kc < 4; kc++) {
            int swv = ((kc * 4 + lq) ^ (lr & 7)) * 8;
            bf16x8 av[4];
#pragma unroll
            for (int dt = 0; dt < 4; dt++)
                av[dt] = *reinterpret_cast<const bf16x8*>(&vtb[(dt * 16 + lr) * 128 + swv]);
#pragma unroll
            for (int mt = 0; mt < 2; mt++) {
                bf16x8 bp = *reinterpret_cast<const bf16x8*>(&pp[mt][kc * 2]);
#pragma unroll
                for (int dt = 0; dt < 4; dt++)
                    o[mt][dt] = __builtin_amdgcn_mfma_f32_16x16x32_bf16(av[dt], bp, o[mt][dt], 0, 0, 0);
            }
        }
    }

    // finalize: lane owns q-col lr in O^T layout
    us* ch = ctx + hoff;
#pragma unroll
    for (int mt = 0; mt < 2; mt++) {
        float ls = (rsv[mt][0] + rsv[mt][1]) + (rsv[mt][2] + rsv[mt][3]);
        ls += __shfl_xor(ls, 16);
        ls += __shfl_xor(ls, 32);
        float linv = 1.0f / ls;
        int row = q0 + mt * 16 + lr;
#pragma unroll
        for (int dt = 0; dt < 4; dt++) {
            ushort4 pk;
            pk.x = f2bf(o[mt][dt][0] * linv);
            pk.y = f2bf(o[mt][dt][1] * linv);
            pk.z = f2bf(o[mt][dt][2] * linv);
            pk.w = f2bf(o[mt][dt][3] * linv);
            *(ushort4*)(ch + (size_t)row * 64 + dt * 16 + lq * 4) = pk;
        }
    }
}

extern "C" void kernel_launch(void* const* d_in, const int* in_sizes, int n_in,
                              void* d_out, int out_size, void* d_ws, size_t ws_size,
                              hipStream_t stream) {
    const float* x  = (const float*)d_in[0];
    const float* Wq = (const float*)d_in[1];
    const float* Wk = (const float*)d_in[2];
    const float* Wv = (const float*)d_in[3];
    const float* Wp = (const float*)d_in[4];
    const float* bp = (const float*)d_in[5];
    float* out = (float*)d_out;

    us* ws = (us*)d_ws;
    us* xb    = ws;                       // MC
    us* WtAll = xb + MC;                  // 4*1048576 (Wq,Wk,Wv,Wp transposed, stacked)
    us* QKV   = WtAll + 4 * 1048576;      // 3*MC (Q, K, V)
    us* VtB   = QKV + 3 * (size_t)MC;     // MC  (V^T per head-block)
    us* ctx   = VtB + MC;                 // MC

    cvt_x<<<MC / 1024, 256, 0, stream>>>(x, xb, MC);
    wtrans<<<dim3(16, 16, 4), 256, 0, stream>>>(Wq, Wk, Wv, Wp, WtAll);
    gemmF<<<dim3(64, 24), 256, 0, stream>>>(xb, WtAll, QKV);
    vtrans<<<dim3(32, 64), 256, 0, stream>>>(QKV + 2 * (size_t)MC, VtB);
    attn<<<dim3(64, 16), 256, 0, stream>>>(QKV, VtB, ctx);
    gemmP<<<dim3(64, 8), 256, 0, stream>>>(ctx, WtAll + 3 * 1048576, out, bp);
}